// Round 20
// baseline (5275.690 us; speedup 1.0000x reference)
//
#include <hip/hip_runtime.h>
#include <cmath>

#define LEAK 0.95f
#define ILEAK 0.05f

typedef float f4 __attribute__((ext_vector_type(4)));
typedef short s8 __attribute__((ext_vector_type(8)));   // 8 bf16 = 4 VGPRs
typedef unsigned long long ull;

// ---------------- Phase 1: u = x @ W_in^T (fp32 tiled GEMM) ----------------
__global__ __launch_bounds__(256) void resv_gemm_uin(
    const float* __restrict__ A, const float* __restrict__ Bm,
    float* __restrict__ C, int M, int N, int K)
{
    __shared__ float As[16][68];
    __shared__ float Bs[16][68];
    const int tid = threadIdx.x;
    const int m0 = blockIdx.y * 64;
    const int n0 = blockIdx.x * 64;
    const int lm = tid >> 2;
    const int lk = (tid & 3) * 4;
    const int ty = tid >> 4;
    const int tx = tid & 15;

    float acc[4][4];
#pragma unroll
    for (int i = 0; i < 4; ++i)
#pragma unroll
        for (int j = 0; j < 4; ++j) acc[i][j] = 0.f;

    const float* Aptr = A + (size_t)(m0 + lm) * K + lk;
    const float* Bptr = Bm + (size_t)(n0 + lm) * K + lk;

    for (int k0 = 0; k0 < K; k0 += 16) {
        float4 av = *(const float4*)(Aptr + k0);
        float4 bv = *(const float4*)(Bptr + k0);
        __syncthreads();
        As[lk + 0][lm] = av.x; As[lk + 1][lm] = av.y;
        As[lk + 2][lm] = av.z; As[lk + 3][lm] = av.w;
        Bs[lk + 0][lm] = bv.x; Bs[lk + 1][lm] = bv.y;
        Bs[lk + 2][lm] = bv.z; Bs[lk + 3][lm] = bv.w;
        __syncthreads();
#pragma unroll
        for (int kk = 0; kk < 16; ++kk) {
            float4 a = *(const float4*)(&As[kk][ty * 4]);
            float4 b = *(const float4*)(&Bs[kk][tx * 4]);
            acc[0][0] += a.x * b.x; acc[0][1] += a.x * b.y; acc[0][2] += a.x * b.z; acc[0][3] += a.x * b.w;
            acc[1][0] += a.y * b.x; acc[1][1] += a.y * b.y; acc[1][2] += a.y * b.z; acc[1][3] += a.y * b.w;
            acc[2][0] += a.z * b.x; acc[2][1] += a.z * b.y; acc[2][2] += a.z * b.z; acc[2][3] += a.z * b.w;
            acc[3][0] += a.w * b.x; acc[3][1] += a.w * b.y; acc[3][2] += a.w * b.z; acc[3][3] += a.w * b.w;
        }
    }
    float* Cp = C + (size_t)(m0 + ty * 4) * N + n0 + tx * 4;
#pragma unroll
    for (int i = 0; i < 4; ++i) {
        float4 v = make_float4(acc[i][0], acc[i][1], acc[i][2], acc[i][3]);
        *(float4*)(Cp + (size_t)i * N) = v;
    }
}

__device__ __forceinline__ ushort f32_to_bf16_rne(float x) {
    unsigned u = __float_as_uint(x);
    return (ushort)((u + 0x7FFFu + ((u >> 16) & 1u)) >> 16);
}

// ---------------- Phase 2: reservoir recurrence, MFMA compute -------------
// BYTE-EXACT round-16 structure (proven best: ~4.5ms recur) with ONE change:
// SINGLE-PHASE poll. r16's sentinel(4)+bulk(12) phases serialize two L3
// round trips after freshness (sentinel detects, then bulk re-loads and
// verifies). Now all 16 pairs are loaded and tag-checked together each
// round: one serialized RTT removed (~700cy/step). Wait-round volume
// returns to 16 loads/lane (r12 measured the volume effect as ~neutral).
// Also attributes r18's residual regression: packed-payload vs phase-count.
__global__ __launch_bounds__(256, 1) void resv_recur(
    const float* __restrict__ Wres,   // [1024][1024]
    float* __restrict__ out,          // [32][2048][1024] (pre-filled with u)
    ull* __restrict__ pairs)          // ws: [2 slots][8 g][1024 h][4 b] pairs
{
    constexpr int H = 1024, S = 2048;
    extern __shared__ char smraw[];
    ushort* Bb  = (ushort*)smraw;               // [4 b][1040] bf16 (8320 B)
    float*  uL  = (float*)(smraw + 8448);       // [2][2048] u dbuf (16 KB)
    float*  red = (float*)(smraw + 8448 + 16384); // [4 q][32 row][4 b] (2 KB)

    const int tid = threadIdx.x;
    const int g  = blockIdx.x & 7;
    const int r  = blockIdx.x >> 3;
    const int h0 = r * 32;
    const int b0 = g * 4;

    const int w  = tid >> 6;           // wave = k-quarter (k in [w*256, +256))
    const int l  = tid & 63;
    const int lg = l >> 4;             // lane-group 0..3
    const int lc = l & 15;             // A-row / B-col / C-col index

    // ---- one-time: W A-fragments, 2 M-tiles x 8 K-tiles, slot k-map
    //      k = w*256 + kt*32 + lg*8 + j (contiguous 8) ----
    s8 Afrag[16];
#pragma unroll
    for (int m = 0; m < 2; ++m)
#pragma unroll
        for (int kt = 0; kt < 8; ++kt) {
            const float* wp = Wres + (size_t)(h0 + m * 16 + lc) * H
                            + (w * 256 + kt * 32 + lg * 8);
            s8 a;
#pragma unroll
            for (int j = 0; j < 8; ++j) a[j] = (short)f32_to_bf16_rne(wp[j]);
            Afrag[m * 8 + kt] = a;
        }

    const int fb  = tid & 3;           // finish: batch
    const int frw = tid >> 2;          // finish: row (tid<128 -> frw<32)
    float pv = 0.f;                    // finish thread's own previous value

    const ushort* bbase = Bb + (size_t)(lc & 3) * 1040 + w * 256 + lg * 8;

    for (int t = 0; t < S; ++t) {
        // ---- stage u[t..t+15] into double buffer (own region, plain) ----
        if ((t & 15) == 0) {
            float* uB = uL + ((t >> 4) & 1) * 2048;
            for (int c = tid; c < 512; c += 256) {
                int rw4 = c & 7, b = (c >> 3) & 3, tt = c >> 5;
                const float4* src =
                    (const float4*)(out + ((size_t)(b0 + b) * S + (t + tt)) * H + h0);
                ((float4*)uB)[(tt * 4 + b) * 8 + rw4] = src[rw4];
            }
        }
        // ---- SINGLE-PHASE poll: 16 pairs/lane, retry until all tags == t --
        {
            const ull* src = pairs + ((size_t)((t & 1) * 8 + g)) * 4096;
            const unsigned tgt = (unsigned)t;
            ull v[16];
            for (;;) {
#pragma unroll
                for (int c = 0; c < 16; ++c)
                    v[c] = __hip_atomic_load(src + c * 256 + tid, __ATOMIC_RELAXED,
                                             __HIP_MEMORY_SCOPE_AGENT);
                int ok = 1;
#pragma unroll
                for (int c = 0; c < 16; ++c)
                    ok &= ((unsigned)(v[c] >> 32) == tgt);
                if (__all(ok)) break;
            }
            // convert to bf16 and store to Bb[b][h] (stride 1040: writes are
            // 2-lanes-per-dword pairs across all 32 banks = conflict-free)
#pragma unroll
            for (int c = 0; c < 16; ++c) {
                int n = c * 256 + tid;           // n = h*4 + b
                Bb[(n & 3) * 1040 + (n >> 2)] =
                    f32_to_bf16_rne(__uint_as_float((unsigned)v[c]));
            }
        }
        __syncthreads();   // barrier 1: Bb complete

        // ---- compute: 16 MFMA per wave (2 M-tiles x 8 K-tiles) ----
        f4 c0 = (f4)(0.f), c1 = (f4)(0.f);
#pragma unroll
        for (int kt = 0; kt < 8; ++kt) {
            s8 bf = *(const s8*)(bbase + kt * 32);
            c0 = __builtin_amdgcn_mfma_f32_16x16x32_bf16(Afrag[kt],     bf, c0, 0, 0, 0);
            c1 = __builtin_amdgcn_mfma_f32_16x16x32_bf16(Afrag[8 + kt], bf, c1, 0, 0, 0);
        }
        // C/D: col=l&15, row=4*(l>>4)+j (m89). Only cols 0..3 are real.
        if (lc < 4) {
#pragma unroll
            for (int j = 0; j < 4; ++j) {
                red[(w * 32 + lg * 4 + j) * 4 + lc]      = c0[j];
                red[(w * 32 + 16 + lg * 4 + j) * 4 + lc] = c1[j];
            }
        }
        __syncthreads();   // barrier 2: red complete

        // ---- finish (tid<128): publish tagged pair, FULL-LINE order ----
        if (tid < 128) {
            float sum = red[(0 * 32 + frw) * 4 + fb] + red[(1 * 32 + frw) * 4 + fb]
                      + red[(2 * 32 + frw) * 4 + fb] + red[(3 * 32 + frw) * 4 + fb];
            float uv = uL[((t >> 4) & 1) * 2048 + (((t & 15) * 4 + fb) << 5) + frw];
            float ns = LEAK * tanhf(uv + sum) + ILEAK * pv;
            pv = ns;
            ull pk = ((ull)(unsigned)(t + 1) << 32) |
                     (ull)__float_as_uint(ns);
            __hip_atomic_store(
                pairs + ((size_t)(((t + 1) & 1) * 8 + g)) * 4096 + h0 * 4 + tid,
                pk, __ATOMIC_RELAXED, __HIP_MEMORY_SCOPE_AGENT);
            out[((size_t)(b0 + fb) * S + t) * H + h0 + frw] = ns;
        }
        __syncthreads();   // barrier 3: publish before any wave polls t+1
    }
}

extern "C" void kernel_launch(void* const* d_in, const int* in_sizes, int n_in,
                              void* d_out, int out_size, void* d_ws, size_t ws_size,
                              hipStream_t stream)
{
    const float* x    = (const float*)d_in[0];   // [32][2048][512]
    const float* Win  = (const float*)d_in[1];   // [1024][512]
    const float* Wres = (const float*)d_in[2];   // [1024][1024]
    float* out = (float*)d_out;                  // [32][2048][1024]

    ull* pairs = (ull*)d_ws;                     // 2*8*4096*8 = 524288 B

    // zero pairs every launch: (tag 0, 0.0f) == step-0 initial state
    hipMemsetAsync(d_ws, 0, 524288, stream);

    // phase 1: u = x @ W_in^T into d_out
    dim3 gemm_grid(1024 / 64, 65536 / 64);
    resv_gemm_uin<<<gemm_grid, 256, 0, stream>>>(x, Win, out, 65536, 1024, 512);

    // phase 2: recurrence. 96KB dynamic LDS pins exactly 1 wg/CU
    // (co-residency of all 256 wgs proven rounds 1-19).
    constexpr int kLds = 96 * 1024;
    hipFuncSetAttribute((const void*)resv_recur,
                        hipFuncAttributeMaxDynamicSharedMemorySize, kLds);
    resv_recur<<<dim3(256), dim3(256), kLds, stream>>>(Wres, out, pairs);
}

// Round 21
// 5192.445 us; speedup vs baseline: 1.0160x; 1.0160x over previous
//
#include <hip/hip_runtime.h>
#include <cmath>

#define LEAK 0.95f
#define ILEAK 0.05f

typedef float f4 __attribute__((ext_vector_type(4)));
typedef short s8 __attribute__((ext_vector_type(8)));   // 8 bf16 = 4 VGPRs
typedef unsigned long long ull;

// ---------------- Phase 1: u = x @ W_in^T (fp32 tiled GEMM) ----------------
__global__ __launch_bounds__(256) void resv_gemm_uin(
    const float* __restrict__ A, const float* __restrict__ Bm,
    float* __restrict__ C, int M, int N, int K)
{
    __shared__ float As[16][68];
    __shared__ float Bs[16][68];
    const int tid = threadIdx.x;
    const int m0 = blockIdx.y * 64;
    const int n0 = blockIdx.x * 64;
    const int lm = tid >> 2;
    const int lk = (tid & 3) * 4;
    const int ty = tid >> 4;
    const int tx = tid & 15;

    float acc[4][4];
#pragma unroll
    for (int i = 0; i < 4; ++i)
#pragma unroll
        for (int j = 0; j < 4; ++j) acc[i][j] = 0.f;

    const float* Aptr = A + (size_t)(m0 + lm) * K + lk;
    const float* Bptr = Bm + (size_t)(n0 + lm) * K + lk;

    for (int k0 = 0; k0 < K; k0 += 16) {
        float4 av = *(const float4*)(Aptr + k0);
        float4 bv = *(const float4*)(Bptr + k0);
        __syncthreads();
        As[lk + 0][lm] = av.x; As[lk + 1][lm] = av.y;
        As[lk + 2][lm] = av.z; As[lk + 3][lm] = av.w;
        Bs[lk + 0][lm] = bv.x; Bs[lk + 1][lm] = bv.y;
        Bs[lk + 2][lm] = bv.z; Bs[lk + 3][lm] = bv.w;
        __syncthreads();
#pragma unroll
        for (int kk = 0; kk < 16; ++kk) {
            float4 a = *(const float4*)(&As[kk][ty * 4]);
            float4 b = *(const float4*)(&Bs[kk][tx * 4]);
            acc[0][0] += a.x * b.x; acc[0][1] += a.x * b.y; acc[0][2] += a.x * b.z; acc[0][3] += a.x * b.w;
            acc[1][0] += a.y * b.x; acc[1][1] += a.y * b.y; acc[1][2] += a.y * b.z; acc[1][3] += a.y * b.w;
            acc[2][0] += a.z * b.x; acc[2][1] += a.z * b.y; acc[2][2] += a.z * b.z; acc[2][3] += a.z * b.w;
            acc[3][0] += a.w * b.x; acc[3][1] += a.w * b.y; acc[3][2] += a.w * b.z; acc[3][3] += a.w * b.w;
        }
    }
    float* Cp = C + (size_t)(m0 + ty * 4) * N + n0 + tx * 4;
#pragma unroll
    for (int i = 0; i < 4; ++i) {
        float4 v = make_float4(acc[i][0], acc[i][1], acc[i][2], acc[i][3]);
        *(float4*)(Cp + (size_t)i * N) = v;
    }
}

__device__ __forceinline__ ushort f32_to_bf16_rne(float x) {
    unsigned u = __float_as_uint(x);
    return (ushort)((u + 0x7FFFu + ((u >> 16) & 1u)) >> 16);
}

// ---------------- Phase 2: reservoir recurrence, MFMA compute -------------
// r16/r20 design with WAVE-PRIVATE QUARTER POLLING: wave w polls exactly the
// pairs of its MFMA k-quarter (h in [w*256, w*256+256), contiguous/coalesced),
// converts into a wave-private LDS region Bq[w], and starts MFMA immediately
// -- barrier 1 DELETED. De-serializes the straggler wait: 3 of 4 waves'
// convert+MFMA overlap the slowest producer's publish; the re-sync moves to
// barrier A (pre-finish), partially hidden under compute. Bq self-RAW within
// the wave is ordered by in-order DS + explicit lgkmcnt(0)+sched_barrier
// (rule #18). red: written pre-A, read post-A, rewritten only post-B. u-stage
// writes pre-A, read post-A. Publish-before-poll: barrier B (r17 lesson).
// Numerics bit-identical to r16 (same fragments, same summation order).
__global__ __launch_bounds__(256, 1) void resv_recur(
    const float* __restrict__ Wres,   // [1024][1024]
    float* __restrict__ out,          // [32][2048][1024] (pre-filled with u)
    ull* __restrict__ pairs)          // ws: [2 slots][8 g][1024 h][4 b] pairs
{
    constexpr int H = 1024, S = 2048;
    extern __shared__ char smraw[];
    ushort* Bq  = (ushort*)smraw;               // [4 w][4 b][272] bf16 (8704 B)
    float*  uL  = (float*)(smraw + 8704);       // [2][2048] u dbuf (16 KB)
    float*  red = (float*)(smraw + 8704 + 16384); // [4 q][32 row][4 b] (2 KB)

    const int tid = threadIdx.x;
    const int g  = blockIdx.x & 7;
    const int r  = blockIdx.x >> 3;
    const int h0 = r * 32;
    const int b0 = g * 4;

    const int w  = tid >> 6;           // wave = k-quarter (k in [w*256, +256))
    const int l  = tid & 63;
    const int lg = l >> 4;             // lane-group 0..3
    const int lc = l & 15;             // A-row / B-col / C-col index

    // ---- one-time: W A-fragments, 2 M-tiles x 8 K-tiles, slot k-map
    //      k = w*256 + kt*32 + lg*8 + j (contiguous 8) ----
    s8 Afrag[16];
#pragma unroll
    for (int m = 0; m < 2; ++m)
#pragma unroll
        for (int kt = 0; kt < 8; ++kt) {
            const float* wp = Wres + (size_t)(h0 + m * 16 + lc) * H
                            + (w * 256 + kt * 32 + lg * 8);
            s8 a;
#pragma unroll
            for (int j = 0; j < 8; ++j) a[j] = (short)f32_to_bf16_rne(wp[j]);
            Afrag[m * 8 + kt] = a;
        }

    const int fb  = tid & 3;           // finish: batch
    const int frw = tid >> 2;          // finish: row (tid<128 -> frw<32)
    float pv = 0.f;                    // finish thread's own previous value

    // wave-private regions / lane-fixed addresses
    ushort* BqW   = Bq + (size_t)w * 4 * 272;           // this wave's region
    ushort* BqWr  = BqW + (l & 3) * 272 + (l >> 2);     // convert write base
    const ushort* bbase = BqW + (size_t)(lc & 3) * 272 + lg * 8;  // MFMA read

    for (int t = 0; t < S; ++t) {
        // ---- stage u[t..t+15] into double buffer (own region, plain) ----
        if ((t & 15) == 0) {
            float* uB = uL + ((t >> 4) & 1) * 2048;
            for (int c = tid; c < 512; c += 256) {
                int rw4 = c & 7, b = (c >> 3) & 3, tt = c >> 5;
                const float4* src =
                    (const float4*)(out + ((size_t)(b0 + b) * S + (t + tt)) * H + h0);
                ((float4*)uB)[(tt * 4 + b) * 8 + rw4] = src[rw4];
            }
        }
        // ---- wave-private poll: 16 contiguous pairs/lane of OWN quarter ----
        {
            const ull* src = pairs + ((size_t)((t & 1) * 8 + g)) * 4096
                           + (size_t)w * 1024 + l;
            const unsigned tgt = (unsigned)t;
            ull v[16];
            for (;;) {
#pragma unroll
                for (int c = 0; c < 16; ++c)
                    v[c] = __hip_atomic_load(src + c * 64, __ATOMIC_RELAXED,
                                             __HIP_MEMORY_SCOPE_AGENT);
                int ok = 1;
#pragma unroll
                for (int c = 0; c < 16; ++c)
                    ok &= ((unsigned)(v[c] >> 32) == tgt);
                if (__all(ok)) break;
            }
            // convert to bf16 into wave-private Bq[w][b=l&3][h'=c*16+(l>>2)]
#pragma unroll
            for (int c = 0; c < 16; ++c)
                BqWr[c * 16] = f32_to_bf16_rne(__uint_as_float((unsigned)v[c]));
        }
        // order own ds_writes before own ds_reads (no barrier; rule #18)
        asm volatile("s_waitcnt lgkmcnt(0)" ::: "memory");
        __builtin_amdgcn_sched_barrier(0);

        // ---- compute: 16 MFMA per wave (2 M-tiles x 8 K-tiles) ----
        f4 c0 = (f4)(0.f), c1 = (f4)(0.f);
#pragma unroll
        for (int kt = 0; kt < 8; ++kt) {
            s8 bf = *(const s8*)(bbase + kt * 32);
            c0 = __builtin_amdgcn_mfma_f32_16x16x32_bf16(Afrag[kt],     bf, c0, 0, 0, 0);
            c1 = __builtin_amdgcn_mfma_f32_16x16x32_bf16(Afrag[8 + kt], bf, c1, 0, 0, 0);
        }
        // C/D: col=l&15, row=4*(l>>4)+j (m89). Only cols 0..3 are real.
        if (lc < 4) {
#pragma unroll
            for (int j = 0; j < 4; ++j) {
                red[(w * 32 + lg * 4 + j) * 4 + lc]      = c0[j];
                red[(w * 32 + 16 + lg * 4 + j) * 4 + lc] = c1[j];
            }
        }
        __syncthreads();   // barrier A: red complete (first wg-wide sync)

        // ---- finish (tid<128): publish tagged pair, FULL-LINE order ----
        if (tid < 128) {
            float sum = red[(0 * 32 + frw) * 4 + fb] + red[(1 * 32 + frw) * 4 + fb]
                      + red[(2 * 32 + frw) * 4 + fb] + red[(3 * 32 + frw) * 4 + fb];
            float uv = uL[((t >> 4) & 1) * 2048 + (((t & 15) * 4 + fb) << 5) + frw];
            float ns = LEAK * tanhf(uv + sum) + ILEAK * pv;
            pv = ns;
            ull pk = ((ull)(unsigned)(t + 1) << 32) |
                     (ull)__float_as_uint(ns);
            __hip_atomic_store(
                pairs + ((size_t)(((t + 1) & 1) * 8 + g)) * 4096 + h0 * 4 + tid,
                pk, __ATOMIC_RELAXED, __HIP_MEMORY_SCOPE_AGENT);
            out[((size_t)(b0 + fb) * S + t) * H + h0 + frw] = ns;
        }
        __syncthreads();   // barrier B: publish issued before any wave polls
                           // t+1; also protects red WAR (rewrite is post-B)
    }
}

extern "C" void kernel_launch(void* const* d_in, const int* in_sizes, int n_in,
                              void* d_out, int out_size, void* d_ws, size_t ws_size,
                              hipStream_t stream)
{
    const float* x    = (const float*)d_in[0];   // [32][2048][512]
    const float* Win  = (const float*)d_in[1];   // [1024][512]
    const float* Wres = (const float*)d_in[2];   // [1024][1024]
    float* out = (float*)d_out;                  // [32][2048][1024]

    ull* pairs = (ull*)d_ws;                     // 2*8*4096*8 = 524288 B

    // zero pairs every launch: (tag 0, 0.0f) == step-0 initial state
    hipMemsetAsync(d_ws, 0, 524288, stream);

    // phase 1: u = x @ W_in^T into d_out
    dim3 gemm_grid(1024 / 64, 65536 / 64);
    resv_gemm_uin<<<gemm_grid, 256, 0, stream>>>(x, Win, out, 65536, 1024, 512);

    // phase 2: recurrence. 96KB dynamic LDS pins exactly 1 wg/CU
    // (co-residency of all 256 wgs proven rounds 1-20).
    constexpr int kLds = 96 * 1024;
    hipFuncSetAttribute((const void*)resv_recur,
                        hipFuncAttributeMaxDynamicSharedMemorySize, kLds);
    resv_recur<<<dim3(256), dim3(256), kLds, stream>>>(Wres, out, pairs);
}

// Round 22
// 4842.229 us; speedup vs baseline: 1.0895x; 1.0723x over previous
//
#include <hip/hip_runtime.h>
#include <cmath>

#define LEAK 0.95f
#define ILEAK 0.05f

typedef float f4 __attribute__((ext_vector_type(4)));
typedef short s8 __attribute__((ext_vector_type(8)));   // 8 bf16 = 4 VGPRs
typedef unsigned long long ull;

__device__ __forceinline__ ushort f32_to_bf16_rne(float x) {
    unsigned u = __float_as_uint(x);
    return (ushort)((u + 0x7FFFu + ((u >> 16) & 1u)) >> 16);
}
__device__ __forceinline__ float bf16_to_f32(ushort h) {
    return __uint_as_float(((unsigned)h) << 16);
}

// ---------------- Phase 1: u = x @ W_in^T (split-precision bf16 MFMA) -----
// x = xh + xl, W = wh + wl (bf16 RNE splits); u = xh*wh + xh*wl + xl*wh
// (dropped xl*wl ~ 2^-18 rel -> u accurate to fp32; absmax unchanged).
// Fragment maps are the recurrence's VERIFIED pattern (r16-r21): A-frag
// row=lc, k=kt*32+lg*8+j; B-frag col=lc, same k-map; C row=4lg+j, col=lc.
// wg = 64 M x 128 N; wave w owns M-subtile rows [16w,16w+16) x all 8 N-tiles.
// W_in chunk (128 cols x 128 k) staged hi/lo in LDS, stride-40 ushort rows
// (16B-aligned lane slots, <=2-way banks on ds_read_b128).
__global__ __launch_bounds__(256, 1) void resv_gemm_mfma(
    const float* __restrict__ A,   // x [65536][512]
    const float* __restrict__ Bm,  // W_in [1024][512]
    float* __restrict__ C)         // u [65536][1024]
{
    constexpr int K = 512;
    extern __shared__ char sm[];
    ushort* Bh = (ushort*)sm;                // [32 ntkt][16 lc][40] (40960 B)
    ushort* Bl = (ushort*)(sm + 40960);      // same shape (40960 B)

    const int tid = threadIdx.x;
    const int n0 = blockIdx.x * 128;
    const int m0 = blockIdx.y * 64;
    const int w  = tid >> 6;
    const int l  = tid & 63;
    const int lg = l >> 4;
    const int lc = l & 15;

    f4 acc[8];
#pragma unroll
    for (int i = 0; i < 8; ++i) acc[i] = (f4)(0.f);

    const int scol = tid >> 1;           // staging col 0..127
    const int skh  = (tid & 1) * 64;     // staging k-half
    const int sntk = scol >> 4;
    const int slc  = scol & 15;

    const float* aprow = A + (size_t)(m0 + 16 * w + lc) * K + lg * 8;

    for (int kc = 0; kc < 4; ++kc) {
        __syncthreads();   // LDS WAR: previous chunk's fragment reads done
        // ---- stage W_in chunk as hi/lo bf16 fragments ----
        {
            const float* bp = Bm + (size_t)(n0 + scol) * K + kc * 128 + skh;
#pragma unroll
            for (int i = 0; i < 16; ++i) {
                float4 v = *(const float4*)(bp + 4 * i);
                int k  = skh + 4 * i;
                int kt = k >> 5, kk = k & 31;
                ushort h0 = f32_to_bf16_rne(v.x);
                ushort h1 = f32_to_bf16_rne(v.y);
                ushort h2 = f32_to_bf16_rne(v.z);
                ushort h3 = f32_to_bf16_rne(v.w);
                ushort q0 = f32_to_bf16_rne(v.x - bf16_to_f32(h0));
                ushort q1 = f32_to_bf16_rne(v.y - bf16_to_f32(h1));
                ushort q2 = f32_to_bf16_rne(v.z - bf16_to_f32(h2));
                ushort q3 = f32_to_bf16_rne(v.w - bf16_to_f32(h3));
                int off = (sntk * 4 + kt) * 640 + slc * 40 + kk;  // ushort units
                *(ull*)(Bh + off) = (ull)h0 | ((ull)h1 << 16)
                                  | ((ull)h2 << 32) | ((ull)h3 << 48);
                *(ull*)(Bl + off) = (ull)q0 | ((ull)q1 << 16)
                                  | ((ull)q2 << 32) | ((ull)q3 << 48);
            }
        }
        __syncthreads();
        // ---- compute: 4 K-tiles x 8 N-tiles x 3 split-MFMAs ----
#pragma unroll
        for (int kt = 0; kt < 4; ++kt) {
            float4 a0 = *(const float4*)(aprow + kc * 128 + kt * 32);
            float4 a1 = *(const float4*)(aprow + kc * 128 + kt * 32 + 4);
            float av[8] = {a0.x, a0.y, a0.z, a0.w, a1.x, a1.y, a1.z, a1.w};
            s8 ah, al;
#pragma unroll
            for (int j = 0; j < 8; ++j) {
                ushort h = f32_to_bf16_rne(av[j]);
                ah[j] = (short)h;
                al[j] = (short)f32_to_bf16_rne(av[j] - bf16_to_f32(h));
            }
#pragma unroll
            for (int nt = 0; nt < 8; ++nt) {
                const int boff = (nt * 4 + kt) * 640 + lc * 40 + lg * 8;
                s8 bh = *(const s8*)(Bh + boff);
                s8 bl = *(const s8*)(Bl + boff);
                acc[nt] = __builtin_amdgcn_mfma_f32_16x16x32_bf16(ah, bh, acc[nt], 0, 0, 0);
                acc[nt] = __builtin_amdgcn_mfma_f32_16x16x32_bf16(ah, bl, acc[nt], 0, 0, 0);
                acc[nt] = __builtin_amdgcn_mfma_f32_16x16x32_bf16(al, bh, acc[nt], 0, 0, 0);
            }
        }
    }
    // ---- epilogue: C/D row=4lg+j, col=lc (verified map) ----
#pragma unroll
    for (int nt = 0; nt < 8; ++nt)
#pragma unroll
        for (int j = 0; j < 4; ++j)
            C[(size_t)(m0 + 16 * w + 4 * lg + j) * 1024 + n0 + nt * 16 + lc] =
                acc[nt][j];
}

// ---------------- Phase 2: reservoir recurrence, MFMA compute -------------
// BYTE-IDENTICAL to round 21 (proven ~4.5ms: wave-private quarter polling,
// tag-poll the data, 2 barriers, full-line publish). At its structural
// latency floor: 2048 serial chip-wide exchanges x ~2.2us (publish-visible
// + detect RTT through L3); five consecutive detect/barrier micro-variants
// measured neutral (r12/r19/r20/r21).
__global__ __launch_bounds__(256, 1) void resv_recur(
    const float* __restrict__ Wres,   // [1024][1024]
    float* __restrict__ out,          // [32][2048][1024] (pre-filled with u)
    ull* __restrict__ pairs)          // ws: [2 slots][8 g][1024 h][4 b] pairs
{
    constexpr int H = 1024, S = 2048;
    extern __shared__ char smraw[];
    ushort* Bq  = (ushort*)smraw;               // [4 w][4 b][272] bf16 (8704 B)
    float*  uL  = (float*)(smraw + 8704);       // [2][2048] u dbuf (16 KB)
    float*  red = (float*)(smraw + 8704 + 16384); // [4 q][32 row][4 b] (2 KB)

    const int tid = threadIdx.x;
    const int g  = blockIdx.x & 7;
    const int r  = blockIdx.x >> 3;
    const int h0 = r * 32;
    const int b0 = g * 4;

    const int w  = tid >> 6;           // wave = k-quarter (k in [w*256, +256))
    const int l  = tid & 63;
    const int lg = l >> 4;             // lane-group 0..3
    const int lc = l & 15;             // A-row / B-col / C-col index

    // ---- one-time: W A-fragments, 2 M-tiles x 8 K-tiles, slot k-map ----
    s8 Afrag[16];
#pragma unroll
    for (int m = 0; m < 2; ++m)
#pragma unroll
        for (int kt = 0; kt < 8; ++kt) {
            const float* wp = Wres + (size_t)(h0 + m * 16 + lc) * H
                            + (w * 256 + kt * 32 + lg * 8);
            s8 a;
#pragma unroll
            for (int j = 0; j < 8; ++j) a[j] = (short)f32_to_bf16_rne(wp[j]);
            Afrag[m * 8 + kt] = a;
        }

    const int fb  = tid & 3;           // finish: batch
    const int frw = tid >> 2;          // finish: row (tid<128 -> frw<32)
    float pv = 0.f;                    // finish thread's own previous value

    ushort* BqW   = Bq + (size_t)w * 4 * 272;           // this wave's region
    ushort* BqWr  = BqW + (l & 3) * 272 + (l >> 2);     // convert write base
    const ushort* bbase = BqW + (size_t)(lc & 3) * 272 + lg * 8;  // MFMA read

    for (int t = 0; t < S; ++t) {
        // ---- stage u[t..t+15] into double buffer (own region, plain) ----
        if ((t & 15) == 0) {
            float* uB = uL + ((t >> 4) & 1) * 2048;
            for (int c = tid; c < 512; c += 256) {
                int rw4 = c & 7, b = (c >> 3) & 3, tt = c >> 5;
                const float4* src =
                    (const float4*)(out + ((size_t)(b0 + b) * S + (t + tt)) * H + h0);
                ((float4*)uB)[(tt * 4 + b) * 8 + rw4] = src[rw4];
            }
        }
        // ---- wave-private poll: 16 contiguous pairs/lane of OWN quarter ----
        {
            const ull* src = pairs + ((size_t)((t & 1) * 8 + g)) * 4096
                           + (size_t)w * 1024 + l;
            const unsigned tgt = (unsigned)t;
            ull v[16];
            for (;;) {
#pragma unroll
                for (int c = 0; c < 16; ++c)
                    v[c] = __hip_atomic_load(src + c * 64, __ATOMIC_RELAXED,
                                             __HIP_MEMORY_SCOPE_AGENT);
                int ok = 1;
#pragma unroll
                for (int c = 0; c < 16; ++c)
                    ok &= ((unsigned)(v[c] >> 32) == tgt);
                if (__all(ok)) break;
            }
#pragma unroll
            for (int c = 0; c < 16; ++c)
                BqWr[c * 16] = f32_to_bf16_rne(__uint_as_float((unsigned)v[c]));
        }
        // order own ds_writes before own ds_reads (no barrier; rule #18)
        asm volatile("s_waitcnt lgkmcnt(0)" ::: "memory");
        __builtin_amdgcn_sched_barrier(0);

        // ---- compute: 16 MFMA per wave (2 M-tiles x 8 K-tiles) ----
        f4 c0 = (f4)(0.f), c1 = (f4)(0.f);
#pragma unroll
        for (int kt = 0; kt < 8; ++kt) {
            s8 bf = *(const s8*)(bbase + kt * 32);
            c0 = __builtin_amdgcn_mfma_f32_16x16x32_bf16(Afrag[kt],     bf, c0, 0, 0, 0);
            c1 = __builtin_amdgcn_mfma_f32_16x16x32_bf16(Afrag[8 + kt], bf, c1, 0, 0, 0);
        }
        if (lc < 4) {
#pragma unroll
            for (int j = 0; j < 4; ++j) {
                red[(w * 32 + lg * 4 + j) * 4 + lc]      = c0[j];
                red[(w * 32 + 16 + lg * 4 + j) * 4 + lc] = c1[j];
            }
        }
        __syncthreads();   // barrier A: red complete

        // ---- finish (tid<128): publish tagged pair, FULL-LINE order ----
        if (tid < 128) {
            float sum = red[(0 * 32 + frw) * 4 + fb] + red[(1 * 32 + frw) * 4 + fb]
                      + red[(2 * 32 + frw) * 4 + fb] + red[(3 * 32 + frw) * 4 + fb];
            float uv = uL[((t >> 4) & 1) * 2048 + (((t & 15) * 4 + fb) << 5) + frw];
            float ns = LEAK * tanhf(uv + sum) + ILEAK * pv;
            pv = ns;
            ull pk = ((ull)(unsigned)(t + 1) << 32) |
                     (ull)__float_as_uint(ns);
            __hip_atomic_store(
                pairs + ((size_t)(((t + 1) & 1) * 8 + g)) * 4096 + h0 * 4 + tid,
                pk, __ATOMIC_RELAXED, __HIP_MEMORY_SCOPE_AGENT);
            out[((size_t)(b0 + fb) * S + t) * H + h0 + frw] = ns;
        }
        __syncthreads();   // barrier B: publish before any wave polls t+1
    }
}

extern "C" void kernel_launch(void* const* d_in, const int* in_sizes, int n_in,
                              void* d_out, int out_size, void* d_ws, size_t ws_size,
                              hipStream_t stream)
{
    const float* x    = (const float*)d_in[0];   // [32][2048][512]
    const float* Win  = (const float*)d_in[1];   // [1024][512]
    const float* Wres = (const float*)d_in[2];   // [1024][1024]
    float* out = (float*)d_out;                  // [32][2048][1024]

    ull* pairs = (ull*)d_ws;                     // 2*8*4096*8 = 524288 B

    // zero pairs every launch: (tag 0, 0.0f) == step-0 initial state
    hipMemsetAsync(d_ws, 0, 524288, stream);

    // phase 1: u = x @ W_in^T via split-precision bf16 MFMA (80 KB LDS)
    constexpr int kGemmLds = 81920;
    hipFuncSetAttribute((const void*)resv_gemm_mfma,
                        hipFuncAttributeMaxDynamicSharedMemorySize, kGemmLds);
    resv_gemm_mfma<<<dim3(8, 1024), 256, kGemmLds, stream>>>(x, Win, out);

    // phase 2: recurrence. 96KB dynamic LDS pins exactly 1 wg/CU
    // (co-residency of all 256 wgs proven rounds 1-21).
    constexpr int kLds = 96 * 1024;
    hipFuncSetAttribute((const void*)resv_recur,
                        hipFuncAttributeMaxDynamicSharedMemorySize, kLds);
    resv_recur<<<dim3(256), dim3(256), kLds, stream>>>(Wres, out, pairs);
}

// Round 23
// 4730.441 us; speedup vs baseline: 1.1153x; 1.0236x over previous
//
#include <hip/hip_runtime.h>
#include <cmath>

#define LEAK 0.95f
#define ILEAK 0.05f

typedef float f4 __attribute__((ext_vector_type(4)));
typedef short s8 __attribute__((ext_vector_type(8)));   // 8 bf16 = 4 VGPRs
typedef unsigned long long ull;

__device__ __forceinline__ ushort f32_to_bf16_rne(float x) {
    unsigned u = __float_as_uint(x);
    return (ushort)((u + 0x7FFFu + ((u >> 16) & 1u)) >> 16);
}
__device__ __forceinline__ float bf16_to_f32(ushort h) {
    return __uint_as_float(((unsigned)h) << 16);
}

// ---------------- Phase 1: u = x @ W_in^T (split-precision bf16 MFMA) -----
// r22 GEMM with ONE change: K-chunk halved 128->64 so LDS drops 80->40KB,
// lifting occupancy 1 -> 2 wgs/CU (r22 had 1 wave/SIMD: every global x load
// and staging op fully exposed; compute floor ~105us vs measured ~435us).
// Same fragments, same per-(nt,kt) summation order, same k-chunk order ->
// bit-identical numerics. x = xh+xl, W = wh+wl; u = xh*wh + xh*wl + xl*wh.
__global__ __launch_bounds__(256, 2) void resv_gemm_mfma(
    const float* __restrict__ A,   // x [65536][512]
    const float* __restrict__ Bm,  // W_in [1024][512]
    float* __restrict__ C)         // u [65536][1024]
{
    constexpr int K = 512;
    extern __shared__ char sm[];
    ushort* Bh = (ushort*)sm;                // [16 ntkt][16 lc][40] (20480 B)
    ushort* Bl = (ushort*)(sm + 20480);      // same shape (20480 B)

    const int tid = threadIdx.x;
    const int n0 = blockIdx.x * 128;
    const int m0 = blockIdx.y * 64;
    const int w  = tid >> 6;
    const int l  = tid & 63;
    const int lg = l >> 4;
    const int lc = l & 15;

    f4 acc[8];
#pragma unroll
    for (int i = 0; i < 8; ++i) acc[i] = (f4)(0.f);

    const int scol = tid >> 1;           // staging col 0..127
    const int skh  = (tid & 1) * 32;     // staging k-half of the 64-chunk
    const int sntk = scol >> 4;
    const int slc  = scol & 15;

    const float* aprow = A + (size_t)(m0 + 16 * w + lc) * K + lg * 8;

    for (int kc = 0; kc < 8; ++kc) {
        __syncthreads();   // LDS WAR: previous chunk's fragment reads done
        // ---- stage W_in chunk (128 cols x 64 k) as hi/lo bf16 fragments ----
        {
            const float* bp = Bm + (size_t)(n0 + scol) * K + kc * 64 + skh;
#pragma unroll
            for (int i = 0; i < 8; ++i) {
                float4 v = *(const float4*)(bp + 4 * i);
                int k  = skh + 4 * i;
                int kt = k >> 5, kk = k & 31;
                ushort h0 = f32_to_bf16_rne(v.x);
                ushort h1 = f32_to_bf16_rne(v.y);
                ushort h2 = f32_to_bf16_rne(v.z);
                ushort h3 = f32_to_bf16_rne(v.w);
                ushort q0 = f32_to_bf16_rne(v.x - bf16_to_f32(h0));
                ushort q1 = f32_to_bf16_rne(v.y - bf16_to_f32(h1));
                ushort q2 = f32_to_bf16_rne(v.z - bf16_to_f32(h2));
                ushort q3 = f32_to_bf16_rne(v.w - bf16_to_f32(h3));
                int off = (sntk * 2 + kt) * 640 + slc * 40 + kk;  // ushort units
                *(ull*)(Bh + off) = (ull)h0 | ((ull)h1 << 16)
                                  | ((ull)h2 << 32) | ((ull)h3 << 48);
                *(ull*)(Bl + off) = (ull)q0 | ((ull)q1 << 16)
                                  | ((ull)q2 << 32) | ((ull)q3 << 48);
            }
        }
        __syncthreads();
        // ---- compute: 2 K-tiles x 8 N-tiles x 3 split-MFMAs ----
#pragma unroll
        for (int kt = 0; kt < 2; ++kt) {
            float4 a0 = *(const float4*)(aprow + kc * 64 + kt * 32);
            float4 a1 = *(const float4*)(aprow + kc * 64 + kt * 32 + 4);
            float av[8] = {a0.x, a0.y, a0.z, a0.w, a1.x, a1.y, a1.z, a1.w};
            s8 ah, al;
#pragma unroll
            for (int j = 0; j < 8; ++j) {
                ushort h = f32_to_bf16_rne(av[j]);
                ah[j] = (short)h;
                al[j] = (short)f32_to_bf16_rne(av[j] - bf16_to_f32(h));
            }
#pragma unroll
            for (int nt = 0; nt < 8; ++nt) {
                const int boff = (nt * 2 + kt) * 640 + lc * 40 + lg * 8;
                s8 bh = *(const s8*)(Bh + boff);
                s8 bl = *(const s8*)(Bl + boff);
                acc[nt] = __builtin_amdgcn_mfma_f32_16x16x32_bf16(ah, bh, acc[nt], 0, 0, 0);
                acc[nt] = __builtin_amdgcn_mfma_f32_16x16x32_bf16(ah, bl, acc[nt], 0, 0, 0);
                acc[nt] = __builtin_amdgcn_mfma_f32_16x16x32_bf16(al, bh, acc[nt], 0, 0, 0);
            }
        }
    }
    // ---- epilogue: C/D row=4lg+j, col=lc (verified map) ----
#pragma unroll
    for (int nt = 0; nt < 8; ++nt)
#pragma unroll
        for (int j = 0; j < 4; ++j)
            C[(size_t)(m0 + 16 * w + 4 * lg + j) * 1024 + n0 + nt * 16 + lc] =
                acc[nt][j];
}

// ---------------- Phase 2: reservoir recurrence, MFMA compute -------------
// BYTE-IDENTICAL to rounds 21/22 (proven ~4.4ms: wave-private quarter
// polling, tag-poll the data, 2 barriers, full-line publish). At its
// structural latency floor: 2048 serial chip-wide exchanges x ~2.15us;
// five consecutive detect/barrier micro-variants measured neutral.
__global__ __launch_bounds__(256, 1) void resv_recur(
    const float* __restrict__ Wres,   // [1024][1024]
    float* __restrict__ out,          // [32][2048][1024] (pre-filled with u)
    ull* __restrict__ pairs)          // ws: [2 slots][8 g][1024 h][4 b] pairs
{
    constexpr int H = 1024, S = 2048;
    extern __shared__ char smraw[];
    ushort* Bq  = (ushort*)smraw;               // [4 w][4 b][272] bf16 (8704 B)
    float*  uL  = (float*)(smraw + 8704);       // [2][2048] u dbuf (16 KB)
    float*  red = (float*)(smraw + 8704 + 16384); // [4 q][32 row][4 b] (2 KB)

    const int tid = threadIdx.x;
    const int g  = blockIdx.x & 7;
    const int r  = blockIdx.x >> 3;
    const int h0 = r * 32;
    const int b0 = g * 4;

    const int w  = tid >> 6;           // wave = k-quarter (k in [w*256, +256))
    const int l  = tid & 63;
    const int lg = l >> 4;             // lane-group 0..3
    const int lc = l & 15;             // A-row / B-col / C-col index

    // ---- one-time: W A-fragments, 2 M-tiles x 8 K-tiles, slot k-map ----
    s8 Afrag[16];
#pragma unroll
    for (int m = 0; m < 2; ++m)
#pragma unroll
        for (int kt = 0; kt < 8; ++kt) {
            const float* wp = Wres + (size_t)(h0 + m * 16 + lc) * H
                            + (w * 256 + kt * 32 + lg * 8);
            s8 a;
#pragma unroll
            for (int j = 0; j < 8; ++j) a[j] = (short)f32_to_bf16_rne(wp[j]);
            Afrag[m * 8 + kt] = a;
        }

    const int fb  = tid & 3;           // finish: batch
    const int frw = tid >> 2;          // finish: row (tid<128 -> frw<32)
    float pv = 0.f;                    // finish thread's own previous value

    ushort* BqW   = Bq + (size_t)w * 4 * 272;           // this wave's region
    ushort* BqWr  = BqW + (l & 3) * 272 + (l >> 2);     // convert write base
    const ushort* bbase = BqW + (size_t)(lc & 3) * 272 + lg * 8;  // MFMA read

    for (int t = 0; t < S; ++t) {
        // ---- stage u[t..t+15] into double buffer (own region, plain) ----
        if ((t & 15) == 0) {
            float* uB = uL + ((t >> 4) & 1) * 2048;
            for (int c = tid; c < 512; c += 256) {
                int rw4 = c & 7, b = (c >> 3) & 3, tt = c >> 5;
                const float4* src =
                    (const float4*)(out + ((size_t)(b0 + b) * S + (t + tt)) * H + h0);
                ((float4*)uB)[(tt * 4 + b) * 8 + rw4] = src[rw4];
            }
        }
        // ---- wave-private poll: 16 contiguous pairs/lane of OWN quarter ----
        {
            const ull* src = pairs + ((size_t)((t & 1) * 8 + g)) * 4096
                           + (size_t)w * 1024 + l;
            const unsigned tgt = (unsigned)t;
            ull v[16];
            for (;;) {
#pragma unroll
                for (int c = 0; c < 16; ++c)
                    v[c] = __hip_atomic_load(src + c * 64, __ATOMIC_RELAXED,
                                             __HIP_MEMORY_SCOPE_AGENT);
                int ok = 1;
#pragma unroll
                for (int c = 0; c < 16; ++c)
                    ok &= ((unsigned)(v[c] >> 32) == tgt);
                if (__all(ok)) break;
            }
#pragma unroll
            for (int c = 0; c < 16; ++c)
                BqWr[c * 16] = f32_to_bf16_rne(__uint_as_float((unsigned)v[c]));
        }
        // order own ds_writes before own ds_reads (no barrier; rule #18)
        asm volatile("s_waitcnt lgkmcnt(0)" ::: "memory");
        __builtin_amdgcn_sched_barrier(0);

        // ---- compute: 16 MFMA per wave (2 M-tiles x 8 K-tiles) ----
        f4 c0 = (f4)(0.f), c1 = (f4)(0.f);
#pragma unroll
        for (int kt = 0; kt < 8; ++kt) {
            s8 bf = *(const s8*)(bbase + kt * 32);
            c0 = __builtin_amdgcn_mfma_f32_16x16x32_bf16(Afrag[kt],     bf, c0, 0, 0, 0);
            c1 = __builtin_amdgcn_mfma_f32_16x16x32_bf16(Afrag[8 + kt], bf, c1, 0, 0, 0);
        }
        if (lc < 4) {
#pragma unroll
            for (int j = 0; j < 4; ++j) {
                red[(w * 32 + lg * 4 + j) * 4 + lc]      = c0[j];
                red[(w * 32 + 16 + lg * 4 + j) * 4 + lc] = c1[j];
            }
        }
        __syncthreads();   // barrier A: red complete

        // ---- finish (tid<128): publish tagged pair, FULL-LINE order ----
        if (tid < 128) {
            float sum = red[(0 * 32 + frw) * 4 + fb] + red[(1 * 32 + frw) * 4 + fb]
                      + red[(2 * 32 + frw) * 4 + fb] + red[(3 * 32 + frw) * 4 + fb];
            float uv = uL[((t >> 4) & 1) * 2048 + (((t & 15) * 4 + fb) << 5) + frw];
            float ns = LEAK * tanhf(uv + sum) + ILEAK * pv;
            pv = ns;
            ull pk = ((ull)(unsigned)(t + 1) << 32) |
                     (ull)__float_as_uint(ns);
            __hip_atomic_store(
                pairs + ((size_t)(((t + 1) & 1) * 8 + g)) * 4096 + h0 * 4 + tid,
                pk, __ATOMIC_RELAXED, __HIP_MEMORY_SCOPE_AGENT);
            out[((size_t)(b0 + fb) * S + t) * H + h0 + frw] = ns;
        }
        __syncthreads();   // barrier B: publish before any wave polls t+1
    }
}

extern "C" void kernel_launch(void* const* d_in, const int* in_sizes, int n_in,
                              void* d_out, int out_size, void* d_ws, size_t ws_size,
                              hipStream_t stream)
{
    const float* x    = (const float*)d_in[0];   // [32][2048][512]
    const float* Win  = (const float*)d_in[1];   // [1024][512]
    const float* Wres = (const float*)d_in[2];   // [1024][1024]
    float* out = (float*)d_out;                  // [32][2048][1024]

    ull* pairs = (ull*)d_ws;                     // 2*8*4096*8 = 524288 B

    // zero pairs every launch: (tag 0, 0.0f) == step-0 initial state
    hipMemsetAsync(d_ws, 0, 524288, stream);

    // phase 1: u = x @ W_in^T via split-precision bf16 MFMA.
    // 40KB LDS -> 2 wgs/CU (r22's 80KB pinned 1 wg/CU, zero latency hiding).
    constexpr int kGemmLds = 40960;
    hipFuncSetAttribute((const void*)resv_gemm_mfma,
                        hipFuncAttributeMaxDynamicSharedMemorySize, kGemmLds);
    resv_gemm_mfma<<<dim3(8, 1024), 256, kGemmLds, stream>>>(x, Win, out);

    // phase 2: recurrence. 96KB dynamic LDS pins exactly 1 wg/CU
    // (co-residency of all 256 wgs proven rounds 1-22).
    constexpr int kLds = 96 * 1024;
    hipFuncSetAttribute((const void*)resv_recur,
                        hipFuncAttributeMaxDynamicSharedMemorySize, kLds);
    resv_recur<<<dim3(256), dim3(256), kLds, stream>>>(Wres, out, pairs);
}